// Round 6
// baseline (280.985 us; speedup 1.0000x reference)
//
#include <hip/hip_runtime.h>
#include <cstdint>
#include <cstddef>

// Problem constants: B=4, S=2048, D=1024, H=4096, M = B*S = 8192.
#define MROWS 8192
#define DDIM  1024
#define HDIM  4096

typedef __bf16 bf16x8 __attribute__((ext_vector_type(8)));
typedef float  f32x4  __attribute__((ext_vector_type(4)));

typedef __attribute__((address_space(1))) void* as1_vp;
typedef __attribute__((address_space(3))) void* as3_vp;

__device__ __forceinline__ unsigned short f2bf(float f) {
  unsigned int u = __builtin_bit_cast(unsigned int, f);
  u += 0x7fffu + ((u >> 16) & 1u);   // RNE
  return (unsigned short)(u >> 16);
}

// fast gelu: tanh-form, exp2+rcp based. |err vs exact erf-gelu| < ~1e-3.
__device__ __forceinline__ float fast_gelu(float x) {
  float x3 = x * x * x;
  float z = 0.7978845608028654f * x + 0.03567740814f * x3;
  float e = __builtin_amdgcn_exp2f(z * 2.8853900817779268f); // exp(2z)
  float t = 1.0f - 2.0f * __builtin_amdgcn_rcpf(e + 1.0f);   // tanh(z)
  return 0.5f * x * (1.0f + t);
}

__device__ __forceinline__ void gld_lds16(const unsigned short* g, unsigned short* lds) {
  __builtin_amdgcn_global_load_lds((as1_vp)(uintptr_t)g, (as3_vp)lds, 16, 0, 0);
}

#define VMW(n)  asm volatile("s_waitcnt vmcnt(" #n ")" ::: "memory")
#define LKW()   asm volatile("s_waitcnt lgkmcnt(0)" ::: "memory")
#define BAR()   asm volatile("s_barrier" ::: "memory")

// pre_kernel: blocks [0,8192) convert W1,W2 fp32->bf16 (float4 granule);
// blocks [8192,10240) do p1 (wave per row) and emit xb.
__global__ __launch_bounds__(256) void pre_kernel(
    const float* __restrict__ x, const float* __restrict__ w1,
    const float* __restrict__ w2, unsigned short* __restrict__ xb,
    unsigned short* __restrict__ w1b, unsigned short* __restrict__ w2b,
    float* __restrict__ p1) {
  if (blockIdx.x < 8192) {
    int i = blockIdx.x * 256 + threadIdx.x;     // 0..2097151
    const float* src; unsigned short* dst; int off;
    if (i < 1048576) { src = w1; dst = w1b; off = i; }
    else             { src = w2; dst = w2b; off = i - 1048576; }
    float4 v = ((const float4*)src)[off];
    ushort4 o;
    o.x = f2bf(v.x); o.y = f2bf(v.y); o.z = f2bf(v.z); o.w = f2bf(v.w);
    ((ushort4*)dst)[off] = o;
    return;
  }
  const int bid = blockIdx.x - 8192;
  const int wave = threadIdx.x >> 6, lane = threadIdx.x & 63;
  const int m = bid * 4 + wave;
  const int b = m >> 11;
  const float4* xrow4 = (const float4*)(x + (size_t)m * DDIM);
  const float4* od4   = (const float4*)(x + ((size_t)b * 2048 + 2) * DDIM);
  ushort4* xbrow4 = (ushort4*)(xb + (size_t)m * DDIM);
  float a0 = 0.f, a1 = 0.f, a2 = 0.f, a3 = 0.f;
#pragma unroll
  for (int it = 0; it < 4; ++it) {
    int g = it * 64 + lane;
    float4 v = xrow4[g];
    ushort4 o; o.x = f2bf(v.x); o.y = f2bf(v.y); o.z = f2bf(v.z); o.w = f2bf(v.w);
    xbrow4[g] = o;
    float4 o0 = od4[g];
    float4 o1 = od4[512 + g];
    float4 o2 = od4[1024 + g];
    float4 o3 = od4[1536 + g];
    a0 += v.x * o0.x + v.y * o0.y + v.z * o0.z + v.w * o0.w;
    a1 += v.x * o1.x + v.y * o1.y + v.z * o1.z + v.w * o1.w;
    a2 += v.x * o2.x + v.y * o2.y + v.z * o2.z + v.w * o2.w;
    a3 += v.x * o3.x + v.y * o3.y + v.z * o3.z + v.w * o3.w;
  }
#pragma unroll
  for (int off = 32; off > 0; off >>= 1) {
    a0 += __shfl_down(a0, off);
    a1 += __shfl_down(a1, off);
    a2 += __shfl_down(a2, off);
    a3 += __shfl_down(a3, off);
  }
  if (lane == 0) {
    float4 r; r.x = a0; r.y = a1; r.z = a2; r.w = a3;
    ((float4*)p1)[m] = r;
  }
}

// ---------------------------------------------------------------------------
// GEMM1 v5: faithful port of the verified 256^2 8-phase template (m201 class).
// BM=BN=256, BK=64 (16 K-tiles), 8 waves (2M x 4N), per-wave C = 128x64.
// LDS: 2 bufs x 2 K-halves x (256 rows x 32 cols bf16) x {A,B} = 128 KB.
// Tile tau lives in buf tau&1. K-half = 32 cols; each half is the proven
// 256x32 rotation-swizzled tile: chunk c of row r at slot (c+(r>>1))&3
// (measured 0 bank conflicts, R4/R5). Staged via 2 x gld_lds16 per half.
//
// Per K-tile, 4 phases; iteration = 2 K-tiles (T even, buf0; T+1, buf1):
//  ph: {ds-reads for THIS phase; stage 1 half; [vmcnt@ph4/8]; BAR; lgkm(0);
//       setprio(1); 16 MFMA; setprio(0); BAR}
//  reads: ph1 B-klo(4)+A[0:4]-klo(4); ph2 A[4:8]-klo(4) [B reused in regs];
//         ph3 B-khi(4)+A[0:4]-khi(4); ph4 A[4:8]-khi(4). Same for T+1 @ph5-8.
// Stage list (1 half/phase): ph1 (T+1).Ahi | ph2 (T+2).Blo | ph3 (T+2).Alo |
//  ph4 (T+2).Bhi | ph5 (T+2).Ahi | ph6 (T+3).Blo | ph7 (T+3).Alo | ph8 (T+3).Bhi
// WAR safety: each stage overwrites a half whose last reader retired at an
//  earlier phase's lgkm(0), which precedes that phase's end-barrier, which
//  precedes this stage's issue. (Checked half-by-half.)
// vmcnt(6) ledger (steady): before ph4-wait, in flight = {prev ph6,7,8} +
//  {ph1..ph4} = 7 halves (14 loads); wait->6 confirms the 4 oldest = ALL of
//  tile T+1 (needed ph5/ph7). Symmetric at ph8 for tile T+2. 3 halves stay
//  in flight -> vmcnt never drains in the loop (T4).
// ---------------------------------------------------------------------------
__global__ __launch_bounds__(512, 2) void gemm1_kernel(
    const unsigned short* __restrict__ xb, const unsigned short* __restrict__ w1b,
    const float* __restrict__ x, const float* __restrict__ b1,
    const float* __restrict__ p1, const float* __restrict__ scale_p,
    unsigned short* __restrict__ hact) {
  __shared__ __align__(16) unsigned short As[4 * 8192];   // [buf][half][256*32] 64 KB
  __shared__ __align__(16) unsigned short Bs[4 * 8192];   // 64 KB

  const int id = blockIdx.x;                 // 512 blocks
  const int xcd = id & 7, w = id >> 3;       // XCD-contiguous m-bands
  const int m0 = (xcd * 4 + (w & 3)) * 256;  // 32 m-tiles
  const int n0 = (w >> 2) * 256;             // 16 n-tiles

  const int tid  = threadIdx.x;
  const int wave = tid >> 6, lane = tid & 63;
  const int quad = lane >> 4, l16 = lane & 15;
  const int wm2  = wave >> 2;                // 0..1 -> 128-row half of C
  const int wn2  = wave & 3;                 // 0..3 -> 64-col slice of C

  // Stage source pointers (per 16B slot s in {tid, 512+tid} of a 256x32 half):
  // r = idx>>2, sl = idx&3, src chunk c = (sl - (r>>1)) & 3; LDS dest linear.
  const unsigned short *gA0, *gA1, *gB0, *gB1;
  {
    int idx = tid;
    int r = idx >> 2, sl = idx & 3, c = (sl - (r >> 1)) & 3;
    gA0 = xb  + (size_t)(m0 + r) * DDIM + c * 8;
    gB0 = w1b + (size_t)(n0 + r) * DDIM + c * 8;
    idx = 512 + tid;
    r = idx >> 2; sl = idx & 3; c = (sl - (r >> 1)) & 3;
    gA1 = xb  + (size_t)(m0 + r) * DDIM + c * 8;
    gB1 = w1b + (size_t)(n0 + r) * DDIM + c * 8;
  }
  const int ldsOff0 = (wave * 64) * 8;         // wave-uniform halfword offsets
  const int ldsOff1 = (512 + wave * 64) * 8;

  // stage half hh (0=klo,1=khi) of tile tt into buf bb
#define STG_A(tt, hh, bb) do {                                      \
    const int _o = (tt) * 64 + (hh) * 32;                           \
    unsigned short* _d = As + ((bb) * 2 + (hh)) * 8192;             \
    gld_lds16(gA0 + _o, _d + ldsOff0);                              \
    gld_lds16(gA1 + _o, _d + ldsOff1);                              \
  } while (0)
#define STG_B(tt, hh, bb) do {                                      \
    const int _o = (tt) * 64 + (hh) * 32;                           \
    unsigned short* _d = Bs + ((bb) * 2 + (hh)) * 8192;             \
    gld_lds16(gB0 + _o, _d + ldsOff0);                              \
    gld_lds16(gB1 + _o, _d + ldsOff1);                              \
  } while (0)

  f32x4 acc[8][4];
  const f32x4 z = {0.f, 0.f, 0.f, 0.f};
#pragma unroll
  for (int i = 0; i < 8; ++i)
#pragma unroll
    for (int j = 0; j < 4; ++j) acc[i][j] = z;

  bf16x8 aS0[4], aS1[4], bS0[4], bS1[4];   // static-indexed (rule #20)

  auto LDB4 = [&](const unsigned short* Bh, bf16x8 (&bb)[4]) {
#pragma unroll
    for (int j = 0; j < 4; ++j) {
      const int rb = wn2 * 64 + j * 16 + l16;
      bb[j] = *(const bf16x8*)(Bh + rb * 32 + ((quad + (rb >> 1)) & 3) * 8);
    }
  };
  auto LDA4 = [&](const unsigned short* Ah, int i0, bf16x8 (&aa)[4]) {
#pragma unroll
    for (int i = 0; i < 4; ++i) {
      const int ra = wm2 * 128 + (i0 + i) * 16 + l16;
      aa[i] = *(const bf16x8*)(Ah + ra * 32 + ((quad + (ra >> 1)) & 3) * 8);
    }
  };
  auto MF16 = [&](int i0, bf16x8 (&aa)[4], bf16x8 (&bb)[4]) {
    __builtin_amdgcn_s_setprio(1);
#pragma unroll
    for (int i = 0; i < 4; ++i)
#pragma unroll
      for (int j = 0; j < 4; ++j)
        acc[i0 + i][j] = __builtin_amdgcn_mfma_f32_16x16x32_bf16(aa[i], bb[j], acc[i0 + i][j], 0, 0, 0);
    __builtin_amdgcn_s_setprio(0);
  };

  const unsigned short* A0lo = As;
  const unsigned short* A0hi = As + 8192;
  const unsigned short* A1lo = As + 16384;
  const unsigned short* A1hi = As + 24576;
  const unsigned short* B0lo = Bs;
  const unsigned short* B0hi = Bs + 8192;
  const unsigned short* B1lo = Bs + 16384;
  const unsigned short* B1hi = Bs + 24576;

  // Prologue: tile0 (4 halves) + tile1 {Blo,Alo,Bhi}; confirm tile0, 3 in flight.
  STG_B(0, 0, 0); STG_A(0, 0, 0); STG_B(0, 1, 0); STG_A(0, 1, 0);
  STG_B(1, 0, 1); STG_A(1, 0, 1); STG_B(1, 1, 1);
  VMW(6); BAR();

#pragma unroll 1
  for (int it = 0; it < 7; ++it) {      // steady iterations: T = 0,2,...,12
    const int T = 2 * it;
    // ph1
    LDB4(B0lo, bS0); LDA4(A0lo, 0, aS0);
    STG_A(T + 1, 1, 1);
    BAR(); LKW(); MF16(0, aS0, bS0); BAR();
    // ph2
    LDA4(A0lo, 4, aS1);
    STG_B(T + 2, 0, 0);
    BAR(); LKW(); MF16(4, aS1, bS0); BAR();
    // ph3
    LDB4(B0hi, bS1); LDA4(A0hi, 0, aS0);
    STG_A(T + 2, 0, 0);
    BAR(); LKW(); MF16(0, aS0, bS1); BAR();
    // ph4
    LDA4(A0hi, 4, aS1);
    STG_B(T + 2, 1, 0);
    VMW(6);
    BAR(); LKW(); MF16(4, aS1, bS1); BAR();
    // ph5
    LDB4(B1lo, bS0); LDA4(A1lo, 0, aS0);
    STG_A(T + 2, 1, 0);
    BAR(); LKW(); MF16(0, aS0, bS0); BAR();
    // ph6
    LDA4(A1lo, 4, aS1);
    STG_B(T + 3, 0, 1);
    BAR(); LKW(); MF16(4, aS1, bS0); BAR();
    // ph7
    LDB4(B1hi, bS1); LDA4(A1hi, 0, aS0);
    STG_A(T + 3, 0, 1);
    BAR(); LKW(); MF16(0, aS0, bS1); BAR();
    // ph8
    LDA4(A1hi, 4, aS1);
    STG_B(T + 3, 1, 1);
    VMW(6);
    BAR(); LKW(); MF16(4, aS1, bS1); BAR();
  }
  // Tail iteration: T=14 (tiles 14,15). Only (15).Ahi remains to stage.
  {
    // ph1
    LDB4(B0lo, bS0); LDA4(A0lo, 0, aS0);
    STG_A(15, 1, 1);
    BAR(); LKW(); MF16(0, aS0, bS0); BAR();
    // ph2
    LDA4(A0lo, 4, aS1);
    BAR(); LKW(); MF16(4, aS1, bS0); BAR();
    // ph3
    LDB4(B0hi, bS1); LDA4(A0hi, 0, aS0);
    BAR(); LKW(); MF16(0, aS0, bS1); BAR();
    // ph4: drain remaining stages (tile 15: Blo,Alo,Bhi from prev ph6-8 + Ahi)
    LDA4(A0hi, 4, aS1);
    VMW(0);
    BAR(); LKW(); MF16(4, aS1, bS1); BAR();
    // ph5
    LDB4(B1lo, bS0); LDA4(A1lo, 0, aS0);
    BAR(); LKW(); MF16(0, aS0, bS0); BAR();
    // ph6
    LDA4(A1lo, 4, aS1);
    BAR(); LKW(); MF16(4, aS1, bS0); BAR();
    // ph7
    LDB4(B1hi, bS1); LDA4(A1hi, 0, aS0);
    BAR(); LKW(); MF16(0, aS0, bS1); BAR();
    // ph8
    LDA4(A1hi, 4, aS1);
    LKW(); MF16(4, aS1, bS1);
  }

  // Epilogue: gelu( acc + b1 + scale*p1*even ), bf16 store to hact.
  const float sc = scale_p[0];
  const int bidx = m0 >> 11;
  const int i1 = (n0 + wn2 * 64) >> 10;      // wave-uniform lora index
  const float* exrow = x + ((size_t)(bidx * 2048 + 1 + 2 * i1)) * DDIM;

  float exv[4], b1v[4]; int nn[4];
#pragma unroll
  for (int j = 0; j < 4; ++j) {
    nn[j]  = n0 + wn2 * 64 + j * 16 + l16;
    exv[j] = exrow[nn[j] & 1023];
    b1v[j] = b1[nn[j]];
  }
#pragma unroll
  for (int i = 0; i < 8; ++i) {
#pragma unroll
    for (int r = 0; r < 4; ++r) {
      const int m = m0 + wm2 * 128 + i * 16 + quad * 4 + r;
      const float pv = p1[(size_t)m * 4 + i1] * sc;
#pragma unroll
      for (int j = 0; j < 4; ++j) {
        float v = acc[i][j][r] + b1v[j] + pv * exv[j];
        hact[(size_t)m * HDIM + nn[j]] = f2bf(fast_gelu(v));
      }
    }
  }
#undef STG_A
#undef STG_B
}

// ---------------------------------------------------------------------------
// GEMM2 (reverted to R4 v4 — best measured 82.3us, MfmaUtil 39%):
// 256m x 128n, BK=64, ring-3, rotated 2-phase body, counted VMW(6),
// 1 barrier/tile + publish barrier. p2 fused on matrix pipe (static-index
// wave-uniform selects — rule #20).
// ---------------------------------------------------------------------------
__global__ __launch_bounds__(512, 2) void gemm2_kernel(
    const unsigned short* __restrict__ hact, const unsigned short* __restrict__ w2b,
    const float* __restrict__ x, const float* __restrict__ b2,
    const float* __restrict__ scale_p, float* __restrict__ out) {
  __shared__ __align__(16) unsigned short As[3 * 256 * 64];   // 96 KB
  __shared__ __align__(16) unsigned short Bs[3 * 128 * 64];   // 48 KB
  __shared__ __align__(16) unsigned short od_lds[1024];       // 2 KB
  __shared__ __align__(16) float p2s[256 * 4];                // 4 KB

  const int id = blockIdx.x;                 // 256 blocks = 1/CU
  const int xcd = id & 7, w = id >> 3;       // 32 blocks per XCD
  const int m0 = (xcd * 4 + (w & 3)) * 256;  // 32 m-tiles
  const int n0 = (w >> 2) * 128;             // 8 n-tiles
  const int tid = threadIdx.x;
  const int wave = tid >> 6, lane = tid & 63, quad = lane >> 4, l16 = lane & 15;
  const int wmq = (wave >> 1) * 64;          // wave m-offset (4 quadrants)
  const int wnq = (wave & 1) * 64;           // wave n-offset (2 halves)
  const bool hi = (wave & 1);                // pacc covers acc rows 2*hi..2*hi+1
  const int bidx = m0 >> 11;
  const int i2 = n0 >> 8;                    // block-uniform lora index

  // preload od row (odd token 4+i2) as bf16: 1024 floats, 4 per thread
  if (tid < 256) {
    const float4* src = (const float4*)(x + ((size_t)(bidx * 2048 + 10 + 2 * i2)) * DDIM);
    float4 v = src[tid];
    ushort4 o; o.x = f2bf(v.x); o.y = f2bf(v.y); o.z = f2bf(v.z); o.w = f2bf(v.w);
    ((ushort4*)od_lds)[tid] = o;
  }
  LKW();   // own od ds_write drained; prologue BAR publishes it

  f32x4 acc[4][4];
  const f32x4 z = {0.f, 0.f, 0.f, 0.f};
#pragma unroll
  for (int i = 0; i < 4; ++i)
#pragma unroll
    for (int j = 0; j < 4; ++j) acc[i][j] = z;
  f32x4 pacc[2] = {z, z};
  const bf16x8 zer8 = __builtin_bit_cast(bf16x8, z);

  const unsigned short *gA[4], *gB[2];
#pragma unroll
  for (int s = 0; s < 4; ++s) {
    int idx = (wave * 4 + s) * 64 + lane;
    int r = idx >> 3, sl = idx & 7, c = (sl - r) & 7;
    gA[s] = hact + (size_t)(m0 + r) * HDIM + c * 8;
  }
#pragma unroll
  for (int s = 0; s < 2; ++s) {
    int idx = (wave * 2 + s) * 64 + lane;
    int r = idx >> 3, sl = idx & 7, c = (sl - r) & 7;
    gB[s] = w2b + (size_t)(n0 + r) * HDIM + c * 8;
  }

#define STAGE2(tt, sb) do {                                   \
    const int _k = (tt) * 64;                                 \
    unsigned short* _a = &As[(sb) * 16384];                   \
    unsigned short* _b = &Bs[(sb) * 8192];                    \
    gld_lds16(gA[0] + _k, _a + (wave * 4 + 0) * 512);         \
    gld_lds16(gA[1] + _k, _a + (wave * 4 + 1) * 512);         \
    gld_lds16(gA[2] + _k, _a + (wave * 4 + 2) * 512);         \
    gld_lds16(gA[3] + _k, _a + (wave * 4 + 3) * 512);         \
    gld_lds16(gB[0] + _k, _b + (wave * 2 + 0) * 512);         \
    gld_lds16(gB[1] + _k, _b + (wave * 2 + 1) * 512);         \
  } while (0)

  auto compute_tile = [&](const unsigned short* __restrict__ Ab,
                          const unsigned short* __restrict__ Bb, int odk) {
#pragma unroll
    for (int kk = 0; kk < 64; kk += 32) {
      bf16x8 a[4], b[4];
      const int cb = (kk >> 3) + quad;
#pragma unroll
      for (int j = 0; j < 4; ++j) {
        const int rb = wnq + j * 16 + l16;
        b[j] = *(const bf16x8*)(Bb + rb * 64 + ((cb + rb) & 7) * 8);
      }
#pragma unroll
      for (int i = 0; i < 4; ++i) {
        const int ra = wmq + i * 16 + l16;
        a[i] = *(const bf16x8*)(Ab + ra * 64 + ((cb + ra) & 7) * 8);
      }
      // fused p2 dot on the matrix pipe (od in column 0 only).
      // STATIC indices + wave-uniform select — no scratch (rule #20).
      {
        bf16x8 odv = *(const bf16x8*)(od_lds + odk + kk + quad * 8);  // quad-broadcast
        bf16x8 bod = (l16 == 0) ? odv : zer8;
        bf16x8 pa0 = hi ? a[2] : a[0];
        bf16x8 pa1 = hi ? a[3] : a[1];
        pacc[0] = __builtin_amdgcn_mfma_f32_16x16x32_bf16(pa0, bod, pacc[0], 0, 0, 0);
        pacc[1] = __builtin_amdgcn_mfma_f32_16x16x32_bf16(pa1, bod, pacc[1], 0, 0, 0);
      }
      __builtin_amdgcn_s_setprio(1);
#pragma unroll
      for (int i = 0; i < 4; ++i)
#pragma unroll
        for (int j = 0; j < 4; ++j)
          acc[i][j] = __builtin_amdgcn_mfma_f32_16x16x32_bf16(a[i], b[j], acc[i][j], 0, 0, 0);
      __builtin_amdgcn_s_setprio(0);
    }
  };

  auto flush_p2 = [&](int seg) {
    const int ibase = hi ? 2 : 0;            // address arithmetic only — legal
    if (l16 == 0) {
#pragma unroll
      for (int ip = 0; ip < 2; ++ip)
#pragma unroll
        for (int e = 0; e < 4; ++e)
          p2s[(wmq + (ibase + ip) * 16 + quad * 4 + e) * 4 + seg] = pacc[ip][e];
    }
    pacc[0] = z; pacc[1] = z;
  };

#define TF2(tt, cb, sb) do {                                  \
    STAGE2((tt) + 2, sb);                                     \
    VMW(6);                                                   \
    BAR();                                                    \
    compute_tile(&As[(cb) * 16384], &Bs[(cb) * 8192], ((tt) * 64) & 1023); \
    if (((tt) & 15) == 15) flush_p2((tt) >> 4);               \
    LKW();                                                    \
    BAR();                                                    \
  } while (0)

  // Prologue: tiles 0,1 in flight (12 loads/wave).
  STAGE2(0, 0);
  STAGE2(1, 1);

#pragma unroll 1
  for (int t = 0; t < 60; t += 3) {     // t multiple of 3 -> buffers constant
    TF2(t + 0, 0, 2);
    TF2(t + 1, 1, 0);
    TF2(t + 2, 2, 1);
  }
  TF2(60, 0, 2);                        // stages tile 62
  TF2(61, 1, 0);                        // stages tile 63 (last)
  // Tail: no more staging.
  VMW(6);  BAR(); compute_tile(&As[2 * 16384], &Bs[2 * 8192], 896);   // t=62
  LKW();   BAR();
  VMW(0);  BAR(); compute_tile(&As[0 * 16384], &Bs[0 * 8192], 960);   // t=63
  flush_p2(3);
  LKW();                                 // own p2s writes drained
  BAR();                                 // p2s visible to all waves

  const float sc = scale_p[0];
  const float* evrow = x + ((size_t)(bidx * 2048 + 9 + 2 * i2)) * DDIM;

  float4 ev[4]; float b2v[4]; int nn[4];
#pragma unroll
  for (int j = 0; j < 4; ++j) {
    nn[j] = n0 + wnq + j * 16 + l16;
    ev[j]  = *(const float4*)(evrow + 4 * (nn[j] & 255));
    b2v[j] = b2[nn[j]];
  }
#pragma unroll
  for (int i = 0; i < 4; ++i) {
#pragma unroll
    for (int r = 0; r < 4; ++r) {
      const int mloc = wmq + i * 16 + quad * 4 + r;
      const int m = m0 + mloc;
      const float4 pv = *(const float4*)(p2s + mloc * 4);  // broadcast across l16
#pragma unroll
      for (int j = 0; j < 4; ++j) {
        float lora = ev[j].x * pv.x + ev[j].y * pv.y + ev[j].z * pv.z + ev[j].w * pv.w;
        out[(size_t)m * DDIM + nn[j]] = acc[i][j][r] + b2v[j] + sc * lora;
      }
    }
  }
#undef TF2
#undef STAGE2
}

extern "C" void kernel_launch(void* const* d_in, const int* in_sizes, int n_in,
                              void* d_out, int out_size, void* d_ws, size_t ws_size,
                              hipStream_t stream) {
  const float* x     = (const float*)d_in[0];
  const float* W1    = (const float*)d_in[1];
  const float* b1    = (const float*)d_in[2];
  const float* W2    = (const float*)d_in[3];
  const float* b2    = (const float*)d_in[4];
  const float* scale = (const float*)d_in[5];
  float* out = (float*)d_out;

  char* ws = (char*)d_ws;
  unsigned short* xb   = (unsigned short*)(ws);                // 16 MiB
  unsigned short* w1b  = (unsigned short*)(ws + 16777216);     //  8 MiB
  unsigned short* w2b  = (unsigned short*)(ws + 25165824);     //  8 MiB
  unsigned short* hact = (unsigned short*)(ws + 33554432);     // 64 MiB
  float*          p1   = (float*)(ws + 100663296);             // 128 KiB

  pre_kernel<<<dim3(10240), dim3(256), 0, stream>>>(x, W1, W2, xb, w1b, w2b, p1);
  gemm1_kernel<<<dim3(512), dim3(512), 0, stream>>>(xb, w1b, x, b1, p1, scale, hact);
  gemm2_kernel<<<dim3(256), dim3(512), 0, stream>>>(hact, w2b, x, b2, scale, out);
}